// Round 7
// baseline (71.889 us; speedup 1.0000x reference)
//
#include <hip/hip_runtime.h>

#define B 32
#define N 1024
#define D 256
#define H 8
#define E 256
#define HE 2048
#define NCH 8   // k_attn / xbar n-chunks

// d_ws float offsets
#define OFF_XPART 0        // [B][8][D]         65536
#define OFF_KBAR  65536    // [B][HE]           65536
#define OFF_U     131072   // [B][H][D]         65536 (scale folded)
#define OFF_VPART 196608   // [B][NCH][H][D]    524288
#define OFF_ZPART 720896   // [B][NCH][H]       2048
#define OFF_RES   722944   // [B][HE]           65536

#define DOT4(a, v) ((a).x * (v).x + (a).y * (v).y + (a).z * (v).z + (a).w * (v).w)

// ---- Xpart[b,p,d] = sum_{n in chunk p} wsum[n]*x[b,n,d] ; full-wave coalesced rows
__global__ __launch_bounds__(512) void k_xbar(const float4* __restrict__ x4,
                                              const float* __restrict__ wsum,
                                              float4* __restrict__ Xpart4) {
    __shared__ float4 ps[8][64];
    int t = threadIdx.x, b = blockIdx.x, p = blockIdx.y;
    int dq = t & 63, rep = t >> 6;   // 8 reps
    float4 acc = make_float4(0.f, 0.f, 0.f, 0.f);
#pragma unroll 4
    for (int i = 0; i < 16; ++i) {
        int n = p * 128 + i * 8 + rep;
        float w = wsum[n];
        float4 xv = x4[(size_t)(b * N + n) * 64 + dq];
        acc.x += w * xv.x; acc.y += w * xv.y; acc.z += w * xv.z; acc.w += w * xv.w;
    }
    ps[rep][dq] = acc;
    __syncthreads();
    if (t < 64) {
        float4 s = ps[0][t];
#pragma unroll
        for (int r = 1; r < 8; ++r) {
            float4 v = ps[r][t];
            s.x += v.x; s.y += v.y; s.z += v.z; s.w += v.w;
        }
        Xpart4[(size_t)(b * 8 + p) * 64 + t] = s;
    }
}

// ---- Kbar[b,he] = Wk[he,:].xbar[b,:] + S*bk[he]  (Xpart reduced during staging)
__global__ __launch_bounds__(256) void k_kbar(const float4* __restrict__ Wk4,
                                              const float* __restrict__ bk,
                                              const float* __restrict__ wsum,
                                              const float4* __restrict__ Xp4,
                                              float* __restrict__ Kbar) {
    __shared__ float Xs[32][260];
    __shared__ float Wks[8][260];
    __shared__ float red[256];
    int t = threadIdx.x, he0 = blockIdx.x * 8;
    red[t] = wsum[t] + wsum[t + 256] + wsum[t + 512] + wsum[t + 768];
#pragma unroll
    for (int j = 0; j < 8; ++j) {
        int i4 = t + j * 256, r = i4 >> 6, c = i4 & 63;
        float4 s4 = make_float4(0.f, 0.f, 0.f, 0.f);
#pragma unroll
        for (int p = 0; p < 8; ++p) {
            float4 v = Xp4[(size_t)(r * 8 + p) * 64 + c];
            s4.x += v.x; s4.y += v.y; s4.z += v.z; s4.w += v.w;
        }
        *(float4*)&Xs[r][c * 4] = s4;
    }
#pragma unroll
    for (int j = 0; j < 2; ++j) {
        int i4 = t + j * 256, r = i4 >> 6, c = i4 & 63;
        *(float4*)&Wks[r][c * 4] = Wk4[(size_t)(he0 + r) * 64 + c];
    }
    __syncthreads();
    for (int s = 128; s > 0; s >>= 1) {
        if (t < s) red[t] += red[t + s];
        __syncthreads();
    }
    float S = red[0];
    int bb = t & 31, rr = t >> 5;
    float a = 0.f;
#pragma unroll 4
    for (int c = 0; c < 64; ++c) {
        float4 xv = *(float4*)&Xs[bb][c * 4];
        float4 w = *(float4*)&Wks[rr][c * 4];
        a += DOT4(w, xv);
    }
    Kbar[(size_t)bb * HE + he0 + rr] = a + S * bk[he0 + rr];
}

// ---- U[b,h,d] = scale * sum_e Wq[h*E+e,d] * Kbar[b,h*E+e]
__global__ __launch_bounds__(256) void k_u(const float4* __restrict__ Wq4,
                                           const float* __restrict__ Kbar,
                                           float* __restrict__ U) {
    __shared__ float psv[256 * 33];
    int t = threadIdx.x, h = blockIdx.x, bg = blockIdx.y, dh = blockIdx.z;
    int dq = t & 31, eg = t >> 5;
    float4 acc[8];
#pragma unroll
    for (int j = 0; j < 8; ++j) acc[j] = make_float4(0.f, 0.f, 0.f, 0.f);
    for (int i = 0; i < 32; ++i) {
        int e = eg * 32 + i;
        float4 wq = Wq4[(size_t)(h * E + e) * 64 + dh * 32 + dq];
#pragma unroll
        for (int j = 0; j < 8; ++j) {
            float kb = Kbar[(size_t)(bg * 8 + j) * HE + h * E + e];
            acc[j].x += kb * wq.x; acc[j].y += kb * wq.y;
            acc[j].z += kb * wq.z; acc[j].w += kb * wq.w;
        }
    }
#pragma unroll
    for (int j = 0; j < 8; ++j) {
        int base = (eg * 32 + dq) * 33 + j * 4;
        psv[base + 0] = acc[j].x; psv[base + 1] = acc[j].y;
        psv[base + 2] = acc[j].z; psv[base + 3] = acc[j].w;
    }
    __syncthreads();
    int dq2 = t & 31, j2 = t >> 5;
    float4 s = make_float4(0.f, 0.f, 0.f, 0.f);
#pragma unroll
    for (int eg2 = 0; eg2 < 8; ++eg2) {
        int base = (eg2 * 32 + dq2) * 33 + j2 * 4;
        s.x += psv[base]; s.y += psv[base + 1]; s.z += psv[base + 2]; s.w += psv[base + 3];
    }
    s.x *= 0.0625f; s.y *= 0.0625f; s.z *= 0.0625f; s.w *= 0.0625f;
    *(float4*)&U[((size_t)(bg * 8 + j2) * H + h) * D + dh * 128 + dq2 * 4] = s;
}

// ---- fused attention: logits + exp + weighted-x accumulate, register-resident.
// Head-fold reduce (verified R6): 3 fold steps collapse the 8-head vector into the
// lane index, 3 butterfly steps across octets; lane L holds head bitrev3(L&7).
__global__ __launch_bounds__(512) void k_attn(const float4* __restrict__ x4,
                                              const float* __restrict__ U,
                                              float* __restrict__ Vpart,
                                              float* __restrict__ Zpart) {
    __shared__ float psv[8 * 64 * 33];   // 67.6 KB
    __shared__ float zred[8][8];
    int t = threadIdx.x, b = blockIdx.x, cch = blockIdx.y;
    int lane = t & 63, w = t >> 6;       // 8 waves
    const float* ub = U + (size_t)b * HE;
    float4 u4[8];
#pragma unroll
    for (int h = 0; h < 8; ++h) u4[h] = *(const float4*)&ub[h * D + lane * 4];
    float4 accV[8];
#pragma unroll
    for (int h = 0; h < 8; ++h) accV[h] = make_float4(0.f, 0.f, 0.f, 0.f);
    float zacc = 0.f;
    bool s0 = lane & 1, s1 = (lane >> 1) & 1, s2 = (lane >> 2) & 1;
    const int BR[8] = {0, 4, 2, 6, 1, 5, 3, 7};   // bitrev3 (involution)

    int n0 = cch * 128 + w * 16;
    const float4* xrow = x4 + ((size_t)b * N + n0) * 64 + lane;
    for (int i = 0; i < 16; i += 2) {
        float4 xa = xrow[(size_t)i * 64];
        float4 xc = xrow[(size_t)(i + 1) * 64];
        float pa[8], pc[8];
#pragma unroll
        for (int h = 0; h < 8; ++h) { pa[h] = DOT4(xa, u4[h]); pc[h] = DOT4(xc, u4[h]); }
#pragma unroll
        for (int j = 0; j < 4; ++j) {
            float ka = s0 ? pa[j + 4] : pa[j], ga = s0 ? pa[j] : pa[j + 4];
            pa[j] = ka + __shfl_xor(ga, 1);
            float kc = s0 ? pc[j + 4] : pc[j], gc = s0 ? pc[j] : pc[j + 4];
            pc[j] = kc + __shfl_xor(gc, 1);
        }
#pragma unroll
        for (int j = 0; j < 2; ++j) {
            float ka = s1 ? pa[j + 2] : pa[j], ga = s1 ? pa[j] : pa[j + 2];
            pa[j] = ka + __shfl_xor(ga, 2);
            float kc = s1 ? pc[j + 2] : pc[j], gc = s1 ? pc[j] : pc[j + 2];
            pc[j] = kc + __shfl_xor(gc, 2);
        }
        {
            float ka = s2 ? pa[1] : pa[0], ga = s2 ? pa[0] : pa[1];
            pa[0] = ka + __shfl_xor(ga, 4);
            float kc = s2 ? pc[1] : pc[0], gc = s2 ? pc[0] : pc[1];
            pc[0] = kc + __shfl_xor(gc, 4);
        }
        pa[0] += __shfl_xor(pa[0], 8);  pc[0] += __shfl_xor(pc[0], 8);
        pa[0] += __shfl_xor(pa[0], 16); pc[0] += __shfl_xor(pc[0], 16);
        pa[0] += __shfl_xor(pa[0], 32); pc[0] += __shfl_xor(pc[0], 32);
        float za = __expf(pa[0]), zc = __expf(pc[0]);   // logits tiny; no max-sub needed
        zacc += za + zc;
#pragma unroll
        for (int h = 0; h < 8; ++h) {
            float zah = __shfl(za, BR[h]);
            float zch = __shfl(zc, BR[h]);
            accV[h].x += zah * xa.x + zch * xc.x;
            accV[h].y += zah * xa.y + zch * xc.y;
            accV[h].z += zah * xa.z + zch * xc.z;
            accV[h].w += zah * xa.w + zch * xc.w;
        }
    }
    // 8-wave combine via padded LDS
#pragma unroll
    for (int h = 0; h < 8; ++h) {
        int base = (w * 64 + lane) * 33 + h * 4;
        psv[base + 0] = accV[h].x; psv[base + 1] = accV[h].y;
        psv[base + 2] = accV[h].z; psv[base + 3] = accV[h].w;
    }
    if (lane < 8) zred[w][BR[lane]] = zacc;
    __syncthreads();
    {
        int dq = t & 63, h = t >> 6;   // 512 items, one per thread
        float4 v = make_float4(0.f, 0.f, 0.f, 0.f);
#pragma unroll
        for (int ww = 0; ww < 8; ++ww) {
            int base = (ww * 64 + dq) * 33 + h * 4;
            v.x += psv[base]; v.y += psv[base + 1]; v.z += psv[base + 2]; v.w += psv[base + 3];
        }
        *(float4*)&Vpart[(((size_t)(b * NCH + cch) * H + h) * 64 + dq) * 4] = v;
    }
    if (t < 8) {
        float z = 0.f;
#pragma unroll
        for (int ww = 0; ww < 8; ++ww) z += zred[ww][t];
        Zpart[((size_t)b * NCH + cch) * H + t] = z;
    }
}

// ---- res[b,he] = (Wv[he,:].vbar[b,h,:])/Z[b,h] + bv[he]  — Vpart reduced inline
__global__ __launch_bounds__(256) void k_result(const float4* __restrict__ Wv4,
                                                const float* __restrict__ bv,
                                                const float4* __restrict__ Vp4,
                                                const float* __restrict__ Zpart,
                                                float* __restrict__ res) {
    __shared__ float Vs[32][260];
    __shared__ float Ws[16][260];
    int t = threadIdx.x, h = blockIdx.x;
    int he0 = h * E + blockIdx.y * 16;
#pragma unroll
    for (int j = 0; j < 8; ++j) {
        int i4 = t + j * 256, r = i4 >> 6, c = i4 & 63;
        float4 s = make_float4(0.f, 0.f, 0.f, 0.f);
#pragma unroll
        for (int cc = 0; cc < 8; ++cc) {
            float4 v = Vp4[((size_t)(r * NCH + cc) * H + h) * 64 + c];
            s.x += v.x; s.y += v.y; s.z += v.z; s.w += v.w;
        }
        *(float4*)&Vs[r][c * 4] = s;
    }
#pragma unroll
    for (int j = 0; j < 4; ++j) {
        int i4 = t + j * 256, r = i4 >> 6, c = i4 & 63;
        *(float4*)&Ws[r][c * 4] = Wv4[(size_t)(he0 + r) * 64 + c];
    }
    __syncthreads();
    int bb = t & 31, rr = t >> 5;
    float a0 = 0.f, a1 = 0.f;
#pragma unroll 4
    for (int c = 0; c < 64; ++c) {
        float4 xv = *(float4*)&Vs[bb][c * 4];
        float4 w0 = *(float4*)&Ws[rr][c * 4];
        float4 w1 = *(float4*)&Ws[rr + 8][c * 4];
        a0 += DOT4(w0, xv);
        a1 += DOT4(w1, xv);
    }
    float zs = 0.f;
#pragma unroll
    for (int cc = 0; cc < 8; ++cc) zs += Zpart[(size_t)(bb * NCH + cc) * H + h];
    float inv = 1.0f / zs;
    res[(size_t)bb * HE + he0 + rr] = a0 * inv + bv[he0 + rr];
    res[(size_t)bb * HE + he0 + rr + 8] = a1 * inv + bv[he0 + rr + 8];
}

// ---- out[b,d] = Wo[d,:].res[b,:] + bo[d]  — full-k per block, no atomics/memset
__global__ __launch_bounds__(256) void k_out(const float4* __restrict__ Wo4,
                                             const float* __restrict__ bo,
                                             const float4* __restrict__ res4,
                                             float* __restrict__ out) {
    __shared__ float Rs[32][260];
    __shared__ float Ws[8][260];
    int t = threadIdx.x, d0 = blockIdx.x * 8;
    int bb = t & 31, rr = t >> 5;
    float a = 0.f;
    for (int ch = 0; ch < 8; ++ch) {
        int k4 = ch * 64;
#pragma unroll
        for (int j = 0; j < 8; ++j) {
            int i4 = t + j * 256, r = i4 >> 6, c = i4 & 63;
            *(float4*)&Rs[r][c * 4] = res4[(size_t)r * 512 + k4 + c];
        }
#pragma unroll
        for (int j = 0; j < 2; ++j) {
            int i4 = t + j * 256, r = i4 >> 6, c = i4 & 63;
            *(float4*)&Ws[r][c * 4] = Wo4[(size_t)(d0 + r) * 512 + k4 + c];
        }
        __syncthreads();
#pragma unroll 4
        for (int c = 0; c < 64; ++c) {
            float4 w = *(float4*)&Ws[rr][c * 4];
            float4 rv = *(float4*)&Rs[bb][c * 4];
            a += DOT4(w, rv);
        }
        __syncthreads();
    }
    out[(size_t)bb * D + d0 + rr] = a + bo[d0 + rr];
}

extern "C" void kernel_launch(void* const* d_in, const int* in_sizes, int n_in,
                              void* d_out, int out_size, void* d_ws, size_t ws_size,
                              hipStream_t stream) {
    const float* x    = (const float*)d_in[0];
    const float* Wq   = (const float*)d_in[1];
    // d_in[2] = bq : softmax-invariant, drops out
    const float* Wk   = (const float*)d_in[3];
    const float* bk   = (const float*)d_in[4];
    const float* Wv   = (const float*)d_in[5];
    const float* bv   = (const float*)d_in[6];
    const float* wsum = (const float*)d_in[7];
    // d_in[8] = bs : softmax-invariant, drops out
    const float* Wo   = (const float*)d_in[9];
    const float* bo   = (const float*)d_in[10];
    float* wsf   = (float*)d_ws;
    float* XPART = wsf + OFF_XPART;
    float* KBAR  = wsf + OFF_KBAR;
    float* U     = wsf + OFF_U;
    float* VPART = wsf + OFF_VPART;
    float* ZPART = wsf + OFF_ZPART;
    float* RES   = wsf + OFF_RES;

    k_xbar<<<dim3(B, 8), 512, 0, stream>>>((const float4*)x, wsum, (float4*)XPART);
    k_kbar<<<256, 256, 0, stream>>>((const float4*)Wk, bk, wsum, (const float4*)XPART, KBAR);
    k_u<<<dim3(H, 4, 2), 256, 0, stream>>>((const float4*)Wq, KBAR, U);
    k_attn<<<dim3(B, NCH), 512, 0, stream>>>((const float4*)x, U, VPART, ZPART);
    k_result<<<dim3(H, 16), 256, 0, stream>>>((const float4*)Wv, bv, (const float4*)VPART, ZPART, RES);
    k_out<<<32, 256, 0, stream>>>((const float4*)Wo, bo, (const float4*)RES, (float*)d_out);
}

// Round 8
// 47.991 us; speedup vs baseline: 1.4979x; 1.4979x over previous
//
#include <hip/hip_runtime.h>

#define B 32
#define N 1024
#define D 256
#define H 8
#define E 256
#define HE 2048
#define NCH 8   // k_attn / xbar n-chunks

// d_ws float offsets
#define OFF_XPART 0        // [B][8][D]         65536
#define OFF_KBAR  65536    // [B][HE]           65536
#define OFF_U     131072   // [B][H][D]         65536 (scale folded)
#define OFF_VPART 196608   // [B][NCH][H][D]    524288
#define OFF_ZPART 720896   // [B][NCH][H]       2048
#define OFF_RES   722944   // [B][HE]           65536

#define DOT4(a, v) ((a).x * (v).x + (a).y * (v).y + (a).z * (v).z + (a).w * (v).w)

// ---- Xpart[b,p,d] = sum_{n in chunk p} wsum[n]*x[b,n,d] ; full-wave coalesced rows
__global__ __launch_bounds__(512) void k_xbar(const float4* __restrict__ x4,
                                              const float* __restrict__ wsum,
                                              float4* __restrict__ Xpart4) {
    __shared__ float4 ps[8][64];
    int t = threadIdx.x, b = blockIdx.x, p = blockIdx.y;
    int dq = t & 63, rep = t >> 6;   // 8 reps
    float4 acc = make_float4(0.f, 0.f, 0.f, 0.f);
#pragma unroll 4
    for (int i = 0; i < 16; ++i) {
        int n = p * 128 + i * 8 + rep;
        float w = wsum[n];
        float4 xv = x4[(size_t)(b * N + n) * 64 + dq];
        acc.x += w * xv.x; acc.y += w * xv.y; acc.z += w * xv.z; acc.w += w * xv.w;
    }
    ps[rep][dq] = acc;
    __syncthreads();
    if (t < 64) {
        float4 s = ps[0][t];
#pragma unroll
        for (int r = 1; r < 8; ++r) {
            float4 v = ps[r][t];
            s.x += v.x; s.y += v.y; s.z += v.z; s.w += v.w;
        }
        Xpart4[(size_t)(b * 8 + p) * 64 + t] = s;
    }
}

// ---- Kbar[b,he] = Wk[he,:].xbar[b,:] + S*bk[he]  (Xpart reduced during staging)
__global__ __launch_bounds__(256) void k_kbar(const float4* __restrict__ Wk4,
                                              const float* __restrict__ bk,
                                              const float* __restrict__ wsum,
                                              const float4* __restrict__ Xp4,
                                              float* __restrict__ Kbar) {
    __shared__ float Xs[32][260];
    __shared__ float Wks[8][260];
    __shared__ float red[256];
    int t = threadIdx.x, he0 = blockIdx.x * 8;
    red[t] = wsum[t] + wsum[t + 256] + wsum[t + 512] + wsum[t + 768];
#pragma unroll
    for (int j = 0; j < 8; ++j) {
        int i4 = t + j * 256, r = i4 >> 6, c = i4 & 63;
        float4 s4 = make_float4(0.f, 0.f, 0.f, 0.f);
#pragma unroll
        for (int p = 0; p < 8; ++p) {
            float4 v = Xp4[(size_t)(r * 8 + p) * 64 + c];
            s4.x += v.x; s4.y += v.y; s4.z += v.z; s4.w += v.w;
        }
        *(float4*)&Xs[r][c * 4] = s4;
    }
#pragma unroll
    for (int j = 0; j < 2; ++j) {
        int i4 = t + j * 256, r = i4 >> 6, c = i4 & 63;
        *(float4*)&Wks[r][c * 4] = Wk4[(size_t)(he0 + r) * 64 + c];
    }
    __syncthreads();
    for (int s = 128; s > 0; s >>= 1) {
        if (t < s) red[t] += red[t + s];
        __syncthreads();
    }
    float S = red[0];
    int bb = t & 31, rr = t >> 5;
    float a = 0.f;
#pragma unroll 4
    for (int c = 0; c < 64; ++c) {
        float4 xv = *(float4*)&Xs[bb][c * 4];
        float4 w = *(float4*)&Wks[rr][c * 4];
        a += DOT4(w, xv);
    }
    Kbar[(size_t)bb * HE + he0 + rr] = a + S * bk[he0 + rr];
}

// ---- U[b,h,d] = scale * sum_e Wq[h*E+e,d] * Kbar[b,h*E+e]
// grid (H, 8 bg of 4 b's, 4 dh of 64 floats) = 256 blocks; unique Wq slices.
__global__ __launch_bounds__(256) void k_u(const float4* __restrict__ Wq4,
                                           const float* __restrict__ Kbar,
                                           float* __restrict__ U) {
    __shared__ float4 ps[16][65];   // [eg][dq*4 + j]
    int t = threadIdx.x, h = blockIdx.x, bg = blockIdx.y, dh = blockIdx.z;
    int dq = t & 15, eg = t >> 4;
    float4 acc[4];
#pragma unroll
    for (int j = 0; j < 4; ++j) acc[j] = make_float4(0.f, 0.f, 0.f, 0.f);
#pragma unroll 4
    for (int i = 0; i < 16; ++i) {
        int e = eg * 16 + i;
        float4 wq = Wq4[(size_t)(h * E + e) * 64 + dh * 16 + dq];
#pragma unroll
        for (int j = 0; j < 4; ++j) {
            float kb = Kbar[(size_t)(bg * 4 + j) * HE + h * E + e];  // uniform -> s_load
            acc[j].x += kb * wq.x; acc[j].y += kb * wq.y;
            acc[j].z += kb * wq.z; acc[j].w += kb * wq.w;
        }
    }
#pragma unroll
    for (int j = 0; j < 4; ++j) ps[eg][dq * 4 + j] = acc[j];
    __syncthreads();
    if (t < 64) {
        int dq2 = t & 15, j2 = t >> 4;
        float4 s = make_float4(0.f, 0.f, 0.f, 0.f);
#pragma unroll
        for (int e2 = 0; e2 < 16; ++e2) {
            float4 v = ps[e2][dq2 * 4 + j2];
            s.x += v.x; s.y += v.y; s.z += v.z; s.w += v.w;
        }
        s.x *= 0.0625f; s.y *= 0.0625f; s.z *= 0.0625f; s.w *= 0.0625f;
        *(float4*)&U[((size_t)(bg * 4 + j2) * H + h) * D + dh * 64 + dq2 * 4] = s;
    }
}

// ---- fused attention: logits + exp + weighted-x accumulate, register-resident.
// Head-fold reduce (verified): 3 fold steps collapse the 8-head vector into the
// lane index, 3 butterfly steps across octets; lane L holds head bitrev3(L&7).
__global__ __launch_bounds__(512) void k_attn(const float4* __restrict__ x4,
                                              const float* __restrict__ U,
                                              float* __restrict__ Vpart,
                                              float* __restrict__ Zpart) {
    __shared__ float psv[8 * 64 * 33];   // 67.6 KB
    __shared__ float zred[8][8];
    int t = threadIdx.x, b = blockIdx.x, cch = blockIdx.y;
    int lane = t & 63, w = t >> 6;       // 8 waves
    const float* ub = U + (size_t)b * HE;
    float4 u4[8];
#pragma unroll
    for (int h = 0; h < 8; ++h) u4[h] = *(const float4*)&ub[h * D + lane * 4];
    float4 accV[8];
#pragma unroll
    for (int h = 0; h < 8; ++h) accV[h] = make_float4(0.f, 0.f, 0.f, 0.f);
    float zacc = 0.f;
    bool s0 = lane & 1, s1 = (lane >> 1) & 1, s2 = (lane >> 2) & 1;
    const int BR[8] = {0, 4, 2, 6, 1, 5, 3, 7};   // bitrev3 (involution)

    int n0 = cch * 128 + w * 16;
    const float4* xrow = x4 + ((size_t)b * N + n0) * 64 + lane;
    for (int i = 0; i < 16; i += 2) {
        float4 xa = xrow[(size_t)i * 64];
        float4 xc = xrow[(size_t)(i + 1) * 64];
        float pa[8], pc[8];
#pragma unroll
        for (int h = 0; h < 8; ++h) { pa[h] = DOT4(xa, u4[h]); pc[h] = DOT4(xc, u4[h]); }
#pragma unroll
        for (int j = 0; j < 4; ++j) {
            float ka = s0 ? pa[j + 4] : pa[j], ga = s0 ? pa[j] : pa[j + 4];
            pa[j] = ka + __shfl_xor(ga, 1);
            float kc = s0 ? pc[j + 4] : pc[j], gc = s0 ? pc[j] : pc[j + 4];
            pc[j] = kc + __shfl_xor(gc, 1);
        }
#pragma unroll
        for (int j = 0; j < 2; ++j) {
            float ka = s1 ? pa[j + 2] : pa[j], ga = s1 ? pa[j] : pa[j + 2];
            pa[j] = ka + __shfl_xor(ga, 2);
            float kc = s1 ? pc[j + 2] : pc[j], gc = s1 ? pc[j] : pc[j + 2];
            pc[j] = kc + __shfl_xor(gc, 2);
        }
        {
            float ka = s2 ? pa[1] : pa[0], ga = s2 ? pa[0] : pa[1];
            pa[0] = ka + __shfl_xor(ga, 4);
            float kc = s2 ? pc[1] : pc[0], gc = s2 ? pc[0] : pc[1];
            pc[0] = kc + __shfl_xor(gc, 4);
        }
        pa[0] += __shfl_xor(pa[0], 8);  pc[0] += __shfl_xor(pc[0], 8);
        pa[0] += __shfl_xor(pa[0], 16); pc[0] += __shfl_xor(pc[0], 16);
        pa[0] += __shfl_xor(pa[0], 32); pc[0] += __shfl_xor(pc[0], 32);
        float za = __expf(pa[0]), zc = __expf(pc[0]);   // logits tiny; no max-sub needed
        zacc += za + zc;
#pragma unroll
        for (int h = 0; h < 8; ++h) {
            float zah = __shfl(za, BR[h]);
            float zch = __shfl(zc, BR[h]);
            accV[h].x += zah * xa.x + zch * xc.x;
            accV[h].y += zah * xa.y + zch * xc.y;
            accV[h].z += zah * xa.z + zch * xc.z;
            accV[h].w += zah * xa.w + zch * xc.w;
        }
    }
    // 8-wave combine via padded LDS
#pragma unroll
    for (int h = 0; h < 8; ++h) {
        int base = (w * 64 + lane) * 33 + h * 4;
        psv[base + 0] = accV[h].x; psv[base + 1] = accV[h].y;
        psv[base + 2] = accV[h].z; psv[base + 3] = accV[h].w;
    }
    if (lane < 8) zred[w][BR[lane]] = zacc;
    __syncthreads();
    {
        int dq = t & 63, h = t >> 6;   // 512 items, one per thread
        float4 v = make_float4(0.f, 0.f, 0.f, 0.f);
#pragma unroll
        for (int ww = 0; ww < 8; ++ww) {
            int base = (ww * 64 + dq) * 33 + h * 4;
            v.x += psv[base]; v.y += psv[base + 1]; v.z += psv[base + 2]; v.w += psv[base + 3];
        }
        *(float4*)&Vpart[(((size_t)(b * NCH + cch) * H + h) * 64 + dq) * 4] = v;
    }
    if (t < 8) {
        float z = 0.f;
#pragma unroll
        for (int ww = 0; ww < 8; ++ww) z += zred[ww][t];
        Zpart[((size_t)b * NCH + cch) * H + t] = z;
    }
}

// ---- res[b,he] = (Wv[he,:].vbar[b,h,:])/Z[b,h] + bv[he]  — Vpart reduced inline.
// h==0 blocks also zero d_out (k_out, a later dispatch, atomically accumulates).
__global__ __launch_bounds__(256) void k_result(const float4* __restrict__ Wv4,
                                                const float* __restrict__ bv,
                                                const float4* __restrict__ Vp4,
                                                const float* __restrict__ Zpart,
                                                float* __restrict__ res,
                                                float4* __restrict__ out4) {
    __shared__ float Vs[32][260];
    __shared__ float Ws[16][260];
    int t = threadIdx.x, h = blockIdx.x;
    if (h == 0 && t < 128) out4[blockIdx.y * 128 + t] = make_float4(0.f, 0.f, 0.f, 0.f);
    int he0 = h * E + blockIdx.y * 16;
#pragma unroll
    for (int j = 0; j < 8; ++j) {
        int i4 = t + j * 256, r = i4 >> 6, c = i4 & 63;
        float4 s = make_float4(0.f, 0.f, 0.f, 0.f);
#pragma unroll
        for (int cc = 0; cc < 8; ++cc) {
            float4 v = Vp4[((size_t)(r * NCH + cc) * H + h) * 64 + c];
            s.x += v.x; s.y += v.y; s.z += v.z; s.w += v.w;
        }
        *(float4*)&Vs[r][c * 4] = s;
    }
#pragma unroll
    for (int j = 0; j < 4; ++j) {
        int i4 = t + j * 256, r = i4 >> 6, c = i4 & 63;
        *(float4*)&Ws[r][c * 4] = Wv4[(size_t)(he0 + r) * 64 + c];
    }
    __syncthreads();
    int bb = t & 31, rr = t >> 5;
    float a0 = 0.f, a1 = 0.f;
#pragma unroll 4
    for (int c = 0; c < 64; ++c) {
        float4 xv = *(float4*)&Vs[bb][c * 4];
        float4 w0 = *(float4*)&Ws[rr][c * 4];
        float4 w1 = *(float4*)&Ws[rr + 8][c * 4];
        a0 += DOT4(w0, xv);
        a1 += DOT4(w1, xv);
    }
    float zs = 0.f;
#pragma unroll
    for (int cc = 0; cc < 8; ++cc) zs += Zpart[(size_t)(bb * NCH + cc) * H + h];
    float inv = 1.0f / zs;
    res[(size_t)bb * HE + he0 + rr] = a0 * inv + bv[he0 + rr];
    res[(size_t)bb * HE + he0 + rr + 8] = a1 * inv + bv[he0 + rr + 8];
}

// ---- out[b,d] += Wo[d,kslice].res[b,kslice] (+bo)  — 256 blocks, out pre-zeroed by k_result
__global__ __launch_bounds__(256) void k_out(const float4* __restrict__ Wo4,
                                             const float* __restrict__ bo,
                                             const float4* __restrict__ res4,
                                             float* __restrict__ out) {
    __shared__ float Rs[32][260];
    __shared__ float Ws[8][260];
    int t = threadIdx.x, d0 = blockIdx.x * 8;
    int k4 = blockIdx.y * 64;
#pragma unroll
    for (int j = 0; j < 8; ++j) {
        int i4 = t + j * 256, r = i4 >> 6, c = i4 & 63;
        *(float4*)&Rs[r][c * 4] = res4[(size_t)r * 512 + k4 + c];
    }
#pragma unroll
    for (int j = 0; j < 2; ++j) {
        int i4 = t + j * 256, r = i4 >> 6, c = i4 & 63;
        *(float4*)&Ws[r][c * 4] = Wo4[(size_t)(d0 + r) * 512 + k4 + c];
    }
    __syncthreads();
    int bb = t & 31, rr = t >> 5;
    float a = 0.f;
#pragma unroll 4
    for (int c = 0; c < 64; ++c) {
        float4 w = *(float4*)&Ws[rr][c * 4];
        float4 rv = *(float4*)&Rs[bb][c * 4];
        a += DOT4(w, rv);
    }
    if (blockIdx.y == 0) a += bo[d0 + rr];
    atomicAdd(&out[(size_t)bb * D + d0 + rr], a);
}

extern "C" void kernel_launch(void* const* d_in, const int* in_sizes, int n_in,
                              void* d_out, int out_size, void* d_ws, size_t ws_size,
                              hipStream_t stream) {
    const float* x    = (const float*)d_in[0];
    const float* Wq   = (const float*)d_in[1];
    // d_in[2] = bq : softmax-invariant, drops out
    const float* Wk   = (const float*)d_in[3];
    const float* bk   = (const float*)d_in[4];
    const float* Wv   = (const float*)d_in[5];
    const float* bv   = (const float*)d_in[6];
    const float* wsum = (const float*)d_in[7];
    // d_in[8] = bs : softmax-invariant, drops out
    const float* Wo   = (const float*)d_in[9];
    const float* bo   = (const float*)d_in[10];
    float* wsf   = (float*)d_ws;
    float* XPART = wsf + OFF_XPART;
    float* KBAR  = wsf + OFF_KBAR;
    float* U     = wsf + OFF_U;
    float* VPART = wsf + OFF_VPART;
    float* ZPART = wsf + OFF_ZPART;
    float* RES   = wsf + OFF_RES;

    k_xbar<<<dim3(B, 8), 512, 0, stream>>>((const float4*)x, wsum, (float4*)XPART);
    k_kbar<<<256, 256, 0, stream>>>((const float4*)Wk, bk, wsum, (const float4*)XPART, KBAR);
    k_u<<<dim3(H, 8, 4), 256, 0, stream>>>((const float4*)Wq, KBAR, U);
    k_attn<<<dim3(B, NCH), 512, 0, stream>>>((const float4*)x, U, VPART, ZPART);
    k_result<<<dim3(H, 16), 256, 0, stream>>>((const float4*)Wv, bv, (const float4*)VPART, ZPART, RES, (float4*)d_out);
    k_out<<<dim3(32, 8), 256, 0, stream>>>((const float4*)Wo, bo, (const float4*)RES, (float*)d_out);
}